// Round 2
// baseline (18850.682 us; speedup 1.0000x reference)
//
#include <hip/hip_runtime.h>
#include <hip/hip_bf16.h>
#include <cstdint>
#include <cstddef>

#define BB 64
#define TT 512
#define DD 1024
#define HH 2048
#define GG 8192   // 4*H
#define KK 3072   // D+H

typedef unsigned short u16;
typedef __attribute__((ext_vector_type(8))) short bf16x8;
typedef __attribute__((ext_vector_type(4))) float f32x4;

__device__ __forceinline__ u16 f2bf(float f) {
  union { float f; uint32_t u; } v; v.f = f;
  uint32_t r = v.u + 0x7FFFu + ((v.u >> 16) & 1u);  // RNE
  return (u16)(r >> 16);
}
__device__ __forceinline__ float bf2f(u16 h) {
  union { uint32_t u; float f; } v; v.u = ((uint32_t)h) << 16; return v.f;
}

__device__ __forceinline__ bf16x8 cvt8(const float* __restrict__ p) {
  float4 a = *(const float4*)p;
  float4 b = *(const float4*)(p + 4);
  bf16x8 r;
  r[0] = (short)f2bf(a.x); r[1] = (short)f2bf(a.y);
  r[2] = (short)f2bf(a.z); r[3] = (short)f2bf(a.w);
  r[4] = (short)f2bf(b.x); r[5] = (short)f2bf(b.y);
  r[6] = (short)f2bf(b.z); r[7] = (short)f2bf(b.w);
  return r;
}

typedef __attribute__((address_space(1))) const unsigned int as1_u32;
typedef __attribute__((address_space(3))) unsigned int as3_u32;
__device__ __forceinline__ void gload16(const u16* g, u16* l) {
  __builtin_amdgcn_global_load_lds((as1_u32*)g, (as3_u32*)l, 16, 0, 0);
}

// ======================= conversion preps =======================
__global__ void conv_w_kernel(const float* __restrict__ W_ih,
                              const float* __restrict__ W_hh,
                              u16* __restrict__ Wc) {
  size_t idx = (size_t)blockIdx.x * blockDim.x + threadIdx.x;
  if (idx >= (size_t)GG * KK / 8) return;
  size_t e = idx * 8;
  int r = (int)(e / KK);
  int k = (int)(e % KK);
  bf16x8 v;
  if (k < DD) v = cvt8(W_ih + (size_t)r * DD + k);
  else        v = cvt8(W_hh + (size_t)r * HH + (k - DD));
  *(bf16x8*)(Wc + e) = v;
}

__global__ void conv_x_kernel(const float* __restrict__ x, u16* __restrict__ xb) {
  size_t idx = (size_t)blockIdx.x * blockDim.x + threadIdx.x;
  if (idx >= (size_t)BB * TT * DD / 8) return;
  size_t e = idx * 8;
  *(bf16x8*)(xb + e) = cvt8(x + e);
}

__global__ void conv_wih_kernel(const float* __restrict__ W, u16* __restrict__ Wb) {
  size_t idx = (size_t)blockIdx.x * blockDim.x + threadIdx.x;
  if (idx >= (size_t)GG * DD / 8) return;
  *(bf16x8*)(Wb + idx * 8) = cvt8(W + idx * 8);
}

// ======================= x_proj GEMM =======================
// C[r=(b*512+t)][g] = sum_d xb[r][d]*Wb[g][d]; stored pre-gathered:
// xp[((t*256+wg)*64+b)*32 + G*8 + jl], where g=(G<<11)|(wg<<3)|jl.
__global__ __launch_bounds__(256)
void xproj_gemm(const u16* __restrict__ A, const u16* __restrict__ Bw,
                u16* __restrict__ xp) {
  __shared__ u16 As[128 * 64];
  __shared__ u16 Bs[128 * 64];
  const int tid = threadIdx.x, wave = tid >> 6, lane = tid & 63;
  const int c = lane & 15, g = lane >> 4;
  const int nt = (int)(blockIdx.x & 63), mt = (int)(blockIdx.x >> 6);
  const size_t m0 = (size_t)mt * 128, n0 = (size_t)nt * 128;
  f32x4 acc[2][8] = {};
  for (int kb = 0; kb < 16; ++kb) {
    const int k0 = kb * 64;
    #pragma unroll
    for (int i = 0; i < 4; ++i) {
      const int cbase = (wave * 4 + i) * 64;
      const int chunk = cbase + lane;          // 0..1023
      const int row = chunk >> 3, slot = chunk & 7;
      const int ks = ((slot ^ (row & 7)) * 8);
      gload16(A + (m0 + row) * 1024 + k0 + ks, As + (size_t)cbase * 8);
      gload16(Bw + (n0 + row) * 1024 + k0 + ks, Bs + (size_t)cbase * 8);
    }
    __syncthreads();
    #pragma unroll
    for (int ks = 0; ks < 2; ++ks) {
      bf16x8 af[2];
      #pragma unroll
      for (int mi = 0; mi < 2; ++mi) {
        const int row = wave * 32 + mi * 16 + c;
        const int slot = (ks * 4 + g) ^ (row & 7);
        af[mi] = *(const bf16x8*)(As + row * 64 + slot * 8);
      }
      #pragma unroll
      for (int ni = 0; ni < 8; ++ni) {
        const int row = ni * 16 + c;
        const int slot = (ks * 4 + g) ^ (row & 7);
        bf16x8 bf = *(const bf16x8*)(Bs + row * 64 + slot * 8);
        acc[0][ni] = __builtin_amdgcn_mfma_f32_16x16x32_bf16(af[0], bf, acc[0][ni], 0, 0, 0);
        acc[1][ni] = __builtin_amdgcn_mfma_f32_16x16x32_bf16(af[1], bf, acc[1][ni], 0, 0, 0);
      }
    }
    __syncthreads();
  }
  #pragma unroll
  for (int mi = 0; mi < 2; ++mi) {
    #pragma unroll
    for (int q = 0; q < 4; ++q) {
      const int rr = (int)m0 + wave * 32 + mi * 16 + g * 4 + q;
      const int b = rr >> 9, t = rr & 511;
      #pragma unroll
      for (int ni = 0; ni < 8; ++ni) {
        const int col = (int)n0 + ni * 16 + c;
        const int G = col >> 11, j = col & 2047, wgi = j >> 3, jl = j & 7;
        xp[(((size_t)t * 256 + wgi) * 64 + b) * 32 + G * 8 + jl] = f2bf(acc[mi][ni][q]);
      }
    }
  }
}

// ======================= persistent LSTM =======================
// 256 WGs x 512 thr, 1 WG/CU. WG owns h-indices j0..j0+7 (32 gate rows).
// W_hh slice lives in LDS (MFMA fragment order). c-state in registers.
__global__ __launch_bounds__(512, 1)
void lstm_persistent(const u16* __restrict__ xp, const float* __restrict__ W_hh,
                     const float* __restrict__ b_ih, const float* __restrict__ b_hh,
                     u16* __restrict__ h0, u16* __restrict__ h1,
                     int* __restrict__ cnt) {
  __shared__ u16 Wlds[64 * 2 * 64 * 8];   // 128 KB: [kb][which][lane][8]
  __shared__ float red[4 * 2 * 64 * 4];   // 8 KB
  __shared__ float gst[64 * 36];          // 9216 B (padded rows)

  const int tid = threadIdx.x;
  const int wave = tid >> 6, lane = tid & 63;
  const int m = wave & 3, khalf = wave >> 2;
  const int c = lane & 15, g = lane >> 4;
  const int wg = blockIdx.x;
  const int j0 = wg * 8;

  // ---- one-time: gather W_hh slice into LDS fragment order (coalesced) ----
  {
    const int r = tid >> 4;              // local row 0..31 (i0-7,f0-7,g0-7,o0-7)
    const int gr = (r < 8) ? (j0 + r) : (r < 16) ? (HH + j0 + r - 8)
                 : (r < 24) ? (2 * HH + j0 + r - 16) : (3 * HH + j0 + r - 24);
    const int which = r >> 4, cc = r & 15;
    const float* src = W_hh + (size_t)gr * HH;
    const int k0 = (tid & 15) * 128;
    for (int k8 = 0; k8 < 16; ++k8) {
      const int k = k0 + k8 * 8;
      bf16x8 v = cvt8(src + k);
      const int ent = ((k >> 5) * 2 + which) * 64 + ((k >> 3) & 3) * 16 + cc;
      *(bf16x8*)(Wlds + (size_t)ent * 8) = v;
    }
  }

  // per-thread consumer identity: (batch tb, local j tj)
  const int tb = tid >> 3, tj = tid & 7;
  const int jg = j0 + tj;
  const float bia = b_ih[jg] + b_hh[jg];
  const float bfa = b_ih[HH + jg] + b_hh[HH + jg];
  const float bga = b_ih[2 * HH + jg] + b_hh[2 * HH + jg];
  const float boa = b_ih[3 * HH + jg] + b_hh[3 * HH + jg];
  float cst = 0.f;

  const int arow = m * 16 + c;
  __syncthreads();

  for (int t = 0; t < TT; ++t) {
    const u16* hs = (t & 1) ? h1 : h0;
    u16* hd = (t & 1) ? h0 : h1;
    f32x4 acc0 = {0.f, 0.f, 0.f, 0.f};
    f32x4 acc1 = {0.f, 0.f, 0.f, 0.f};
    const u16* hrow = hs + (size_t)arow * HH;
    #pragma unroll 8
    for (int i = 0; i < 32; ++i) {
      const int kb = khalf * 32 + i;
      bf16x8 a = *(const bf16x8*)(hrow + kb * 32 + g * 8);
      bf16x8 b0 = *(const bf16x8*)(Wlds + (size_t)((kb * 2 + 0) * 64 + lane) * 8);
      bf16x8 b1 = *(const bf16x8*)(Wlds + (size_t)((kb * 2 + 1) * 64 + lane) * 8);
      acc0 = __builtin_amdgcn_mfma_f32_16x16x32_bf16(a, b0, acc0, 0, 0, 0);
      acc1 = __builtin_amdgcn_mfma_f32_16x16x32_bf16(a, b1, acc1, 0, 0, 0);
    }
    if (khalf == 1) {
      #pragma unroll
      for (int q = 0; q < 4; ++q) {
        red[((m * 2 + 0) * 64 + lane) * 4 + q] = acc0[q];
        red[((m * 2 + 1) * 64 + lane) * 4 + q] = acc1[q];
      }
    }
    __syncthreads();
    if (khalf == 0) {
      #pragma unroll
      for (int q = 0; q < 4; ++q) {
        acc0[q] += red[((m * 2 + 0) * 64 + lane) * 4 + q];
        acc1[q] += red[((m * 2 + 1) * 64 + lane) * 4 + q];
        const int b = m * 16 + g * 4 + q;
        gst[b * 36 + c] = acc0[q];        // i (c<8) | f (c>=8)
        gst[b * 36 + 16 + c] = acc1[q];   // g (c<8) | o (c>=8)
      }
    }
    __syncthreads();
    {
      const u16* xv = xp + (((size_t)t * 256 + wg) * 64 + tb) * 32;
      const float ip = gst[tb * 36 + tj]       + bia + bf2f(xv[tj]);
      const float fp = gst[tb * 36 + 8 + tj]   + bfa + bf2f(xv[8 + tj]);
      const float gp = gst[tb * 36 + 16 + tj]  + bga + bf2f(xv[16 + tj]);
      const float op = gst[tb * 36 + 24 + tj]  + boa + bf2f(xv[24 + tj]);
      const float ig = 1.f / (1.f + expf(-ip));
      const float fg = 1.f / (1.f + expf(-fp));
      const float gv = tanhf(gp);
      const float og = 1.f / (1.f + expf(-op));
      cst = fg * cst + ig * gv;
      hd[(size_t)tb * HH + jg] = f2bf(og * tanhf(cst));
    }
    // ---- grid barrier (monotonic counter), with device-scope fences ----
    __threadfence();
    __syncthreads();
    if (tid == 0) {
      __hip_atomic_fetch_add(cnt, 1, __ATOMIC_RELAXED, __HIP_MEMORY_SCOPE_AGENT);
      const int target = (t + 1) * 256;
      while (__hip_atomic_load(cnt, __ATOMIC_RELAXED, __HIP_MEMORY_SCOPE_AGENT) < target) {
        __builtin_amdgcn_s_sleep(1);
      }
    }
    __syncthreads();
    __threadfence();
  }
}

// ======================= fallback per-step kernel (round-1, proven) =======================
template<int MODE>
__global__ __launch_bounds__(512)
void lstm_step_kernel(const float* __restrict__ x, const u16* __restrict__ xb,
                      const float* __restrict__ W_ih, const float* __restrict__ W_hh,
                      const u16* __restrict__ Wc,
                      const float* __restrict__ b_ih, const float* __restrict__ b_hh,
                      const u16* __restrict__ h_src, u16* __restrict__ h_dst,
                      float* __restrict__ cbuf, int t) {
  const int tid = threadIdx.x;
  const int wave = tid >> 6, lane = tid & 63;
  const int m = wave & 3, khalf = wave >> 2;
  const int j0 = blockIdx.x * 8;
  const int c = lane & 15;
  const int arow = m * 16 + c;
  const int koff = (lane >> 4) * 8;
  const int r0 = (c < 8) ? (j0 + c) : (HH + j0 + c - 8);
  const int r1 = (c < 8) ? (2 * HH + j0 + c) : (3 * HH + j0 + c - 8);

  f32x4 acc0 = {0.f, 0.f, 0.f, 0.f};
  f32x4 acc1 = {0.f, 0.f, 0.f, 0.f};

  if (khalf == 0) {
    const size_t xrow = ((size_t)arow * TT + t) * DD;
    #pragma unroll 4
    for (int kb = 0; kb < 32; ++kb) {
      const int k = kb * 32 + koff;
      bf16x8 a;
      if constexpr (MODE == 2) a = *(const bf16x8*)(xb + xrow + k);
      else                     a = cvt8(x + xrow + k);
      bf16x8 b0, b1;
      if constexpr (MODE >= 1) {
        b0 = *(const bf16x8*)(Wc + (size_t)r0 * KK + k);
        b1 = *(const bf16x8*)(Wc + (size_t)r1 * KK + k);
      } else {
        b0 = cvt8(W_ih + (size_t)r0 * DD + k);
        b1 = cvt8(W_ih + (size_t)r1 * DD + k);
      }
      acc0 = __builtin_amdgcn_mfma_f32_16x16x32_bf16(a, b0, acc0, 0, 0, 0);
      acc1 = __builtin_amdgcn_mfma_f32_16x16x32_bf16(a, b1, acc1, 0, 0, 0);
    }
    #pragma unroll 4
    for (int kb = 0; kb < 16; ++kb) {
      const int kh = kb * 32 + koff;
      bf16x8 a = *(const bf16x8*)(h_src + (size_t)arow * HH + kh);
      bf16x8 b0, b1;
      if constexpr (MODE >= 1) {
        b0 = *(const bf16x8*)(Wc + (size_t)r0 * KK + DD + kh);
        b1 = *(const bf16x8*)(Wc + (size_t)r1 * KK + DD + kh);
      } else {
        b0 = cvt8(W_hh + (size_t)r0 * HH + kh);
        b1 = cvt8(W_hh + (size_t)r1 * HH + kh);
      }
      acc0 = __builtin_amdgcn_mfma_f32_16x16x32_bf16(a, b0, acc0, 0, 0, 0);
      acc1 = __builtin_amdgcn_mfma_f32_16x16x32_bf16(a, b1, acc1, 0, 0, 0);
    }
  } else {
    #pragma unroll 4
    for (int kb = 0; kb < 48; ++kb) {
      const int kh = 512 + kb * 32 + koff;
      bf16x8 a = *(const bf16x8*)(h_src + (size_t)arow * HH + kh);
      bf16x8 b0, b1;
      if constexpr (MODE >= 1) {
        b0 = *(const bf16x8*)(Wc + (size_t)r0 * KK + DD + kh);
        b1 = *(const bf16x8*)(Wc + (size_t)r1 * KK + DD + kh);
      } else {
        b0 = cvt8(W_hh + (size_t)r0 * HH + kh);
        b1 = cvt8(W_hh + (size_t)r1 * HH + kh);
      }
      acc0 = __builtin_amdgcn_mfma_f32_16x16x32_bf16(a, b0, acc0, 0, 0, 0);
      acc1 = __builtin_amdgcn_mfma_f32_16x16x32_bf16(a, b1, acc1, 0, 0, 0);
    }
  }

  __shared__ float red[4][2][64][4];
  if (khalf == 1) {
    #pragma unroll
    for (int q = 0; q < 4; ++q) { red[m][0][lane][q] = acc0[q]; red[m][1][lane][q] = acc1[q]; }
  }
  __syncthreads();
  if (khalf == 1) return;
  #pragma unroll
  for (int q = 0; q < 4; ++q) { acc0[q] += red[m][0][lane][q]; acc1[q] += red[m][1][lane][q]; }

  const float bias0 = b_ih[r0] + b_hh[r0];
  const float bias1 = b_ih[r1] + b_hh[r1];
  #pragma unroll
  for (int q = 0; q < 4; ++q) { acc0[q] += bias0; acc1[q] += bias1; }

  float fpre[4], opre[4];
  #pragma unroll
  for (int q = 0; q < 4; ++q) {
    fpre[q] = __shfl_xor(acc0[q], 8);
    opre[q] = __shfl_xor(acc1[q], 8);
  }

  if (c < 8) {
    const int j = j0 + c;
    #pragma unroll
    for (int q = 0; q < 4; ++q) {
      const int b = m * 16 + (lane >> 4) * 4 + q;
      const float ig = 1.f / (1.f + expf(-acc0[q]));
      const float fg = 1.f / (1.f + expf(-fpre[q]));
      const float gg = tanhf(acc1[q]);
      const float og = 1.f / (1.f + expf(-opre[q]));
      const float cold = cbuf[(size_t)b * HH + j];
      const float cn = fg * cold + ig * gg;
      cbuf[(size_t)b * HH + j] = cn;
      h_dst[(size_t)b * HH + j] = f2bf(og * tanhf(cn));
    }
  }
}

// ======================= head =======================
__global__ __launch_bounds__(256)
void head_kernel(const u16* __restrict__ hfin, const float* __restrict__ W_head,
                 const float* __restrict__ b_head, float* __restrict__ out) {
  const int tid = threadIdx.x, wave = tid >> 6, lane = tid & 63;
  const int m = wave;
  const int c = lane & 15;
  const int koff = (lane >> 4) * 8;
  const int d = blockIdx.x * 16 + c;
  const int arow = m * 16 + c;
  f32x4 acc = {0.f, 0.f, 0.f, 0.f};
  #pragma unroll 4
  for (int kb = 0; kb < 64; ++kb) {
    const int k = kb * 32 + koff;
    bf16x8 a = *(const bf16x8*)(hfin + (size_t)arow * HH + k);
    bf16x8 b = cvt8(W_head + (size_t)d * HH + k);
    acc = __builtin_amdgcn_mfma_f32_16x16x32_bf16(a, b, acc, 0, 0, 0);
  }
  const float bh = b_head[d];
  #pragma unroll
  for (int q = 0; q < 4; ++q) {
    const int b = m * 16 + (lane >> 4) * 4 + q;
    out[(size_t)b * DD + d] = acc[q] + bh;
  }
}

extern "C" void kernel_launch(void* const* d_in, const int* in_sizes, int n_in,
                              void* d_out, int out_size, void* d_ws, size_t ws_size,
                              hipStream_t stream) {
  const float* x      = (const float*)d_in[0];
  const float* W_ih   = (const float*)d_in[1];
  const float* W_hh   = (const float*)d_in[2];
  const float* b_ih   = (const float*)d_in[3];
  const float* b_hh   = (const float*)d_in[4];
  const float* W_head = (const float*)d_in[5];
  const float* b_head = (const float*)d_in[6];
  float* out = (float*)d_out;

  char* ws = (char*)d_ws;
  // common low region
  u16* h0 = (u16*)(ws + 0);                       // 256 KB
  u16* h1 = (u16*)(ws + (size_t)BB * HH * 2);     // 256 KB
  float* cbuf = (float*)(ws + 512 * 1024);        // 512 KB (fallback only)
  int* cnt = (int*)(ws + 768 * 1024);             // barrier counter (mode A)

  // MODE A layout
  u16* wihb = (u16*)(ws + (1u << 20));                   // 16 MB @ 1 MB
  u16* xbA  = (u16*)(ws + (64ull << 20));                // 64 MB @ 64 MB
  u16* xp   = (u16*)(ws + (128ull << 20));               // 512 MB @ 128 MB
  const size_t NEED_A = (128ull << 20) + ((size_t)TT * BB * GG * 2);  // 640 MB

  // fallback (round-1) layout
  u16* Wc = (u16*)(ws + (1u << 20));                     // 48 MB @ 1 MB
  u16* xbF = (u16*)(ws + (49ull << 20));                 // 64 MB @ 49 MB

  hipMemsetAsync(ws, 0, 1u << 20, stream);

  if (ws_size >= NEED_A) {
    // ---- MODE A: persistent weight-stationary LSTM ----
    {
      const int n8 = (int)((size_t)BB * TT * DD / 8);
      conv_x_kernel<<<(n8 + 255) / 256, 256, 0, stream>>>(x, xbA);
    }
    {
      const int n8 = (int)((size_t)GG * DD / 8);
      conv_wih_kernel<<<(n8 + 255) / 256, 256, 0, stream>>>(W_ih, wihb);
    }
    xproj_gemm<<<16384, 256, 0, stream>>>(xbA, wihb, xp);

    const u16* xp_ = xp; const float* whh_ = W_hh;
    const float* bih_ = b_ih; const float* bhh_ = b_hh;
    u16* h0_ = h0; u16* h1_ = h1; int* cnt_ = cnt;
    void* kargs[] = {(void*)&xp_, (void*)&whh_, (void*)&bih_, (void*)&bhh_,
                     (void*)&h0_, (void*)&h1_, (void*)&cnt_};
    hipError_t ce = hipLaunchCooperativeKernel((const void*)lstm_persistent,
                                               dim3(256), dim3(512), kargs, 0u, stream);
    if (ce != hipSuccess) {
      (void)hipGetLastError();
      // 1 WG/CU is forced by 145 KB LDS; 256 WGs co-reside on 256 CUs.
      lstm_persistent<<<dim3(256), dim3(512), 0, stream>>>(xp, W_hh, b_ih, b_hh, h0, h1, cnt);
    }
    head_kernel<<<64, 256, 0, stream>>>(h0, W_head, b_head, out);
    return;
  }

  // ---- fallback: round-1 per-step path ----
  int mode = 0;
  if (ws_size >= (49ull << 20) + (size_t)BB * TT * DD * 2)      mode = 2;
  else if (ws_size >= (1ull << 20) + (size_t)GG * KK * 2)       mode = 1;

  if (mode >= 1) {
    const int n8 = (int)((size_t)GG * KK / 8);
    conv_w_kernel<<<(n8 + 255) / 256, 256, 0, stream>>>(W_ih, W_hh, Wc);
  }
  if (mode == 2) {
    const int n8 = (int)((size_t)BB * TT * DD / 8);
    conv_x_kernel<<<(n8 + 255) / 256, 256, 0, stream>>>(x, xbF);
  }

  for (int t = 0; t < TT; ++t) {
    u16* hs = (t & 1) ? h1 : h0;
    u16* hd = (t & 1) ? h0 : h1;
    if (mode == 2)
      lstm_step_kernel<2><<<256, 512, 0, stream>>>(x, xbF, W_ih, W_hh, Wc, b_ih, b_hh, hs, hd, cbuf, t);
    else if (mode == 1)
      lstm_step_kernel<1><<<256, 512, 0, stream>>>(x, xbF, W_ih, W_hh, Wc, b_ih, b_hh, hs, hd, cbuf, t);
    else
      lstm_step_kernel<0><<<256, 512, 0, stream>>>(x, xbF, W_ih, W_hh, Wc, b_ih, b_hh, hs, hd, cbuf, t);
  }
  head_kernel<<<64, 256, 0, stream>>>(h0, W_head, b_head, out);
}